// Round 5
// baseline (112.936 us; speedup 1.0000x reference)
//
#include <hip/hip_runtime.h>
#include <stdint.h>

typedef unsigned short u16t;
typedef __attribute__((ext_vector_type(8))) short bf16x8;
typedef __attribute__((ext_vector_type(4))) float f32x4;
typedef __attribute__((ext_vector_type(16))) float f32x16;

__device__ __forceinline__ float2 up2(uint32_t u) {
    return make_float2(__uint_as_float(u << 16), __uint_as_float(u & 0xFFFF0000u));
}
__device__ __forceinline__ uint32_t pk_bf16(float a, float b) {
    uint32_t r;
    asm("v_cvt_pk_bf16_f32 %0, %1, %2" : "=v"(r) : "v"(a), "v"(b));
    return r;   // lo16 = bf16(a) RNE, hi16 = bf16(b)
}

// ---------------------------------------------------------------------------
// Pre-kernel (35 blocks):
//  blocks 0-31 : W1d (1024x64 fp32) -> Wt bf16 [g][k][o][j]   (131072 B)
//  blocks 32-34: W2d (16x384 fp32)  -> W2b bf16 [16][384] row-major (12288 B)
// ---------------------------------------------------------------------------
__global__ void __launch_bounds__(256) prep_weights(const float* __restrict__ W1d,
                                                    const float* __restrict__ W2d,
                                                    u16t* __restrict__ Wt,
                                                    uint4* __restrict__ W2b) {
    int bid = blockIdx.x;
    if (bid < 32) {
        int t = bid * 256 + threadIdx.x;          // 0..8191
        int g = t >> 10, k = (t >> 7) & 7, o = t & 127;
        const float* src = W1d + (((g << 7) + o) << 6) + (k << 3);
        u16t* dst = Wt + ((((g << 3) + k) << 7) + o) * 8;
#pragma unroll
        for (int j = 0; j < 8; ++j) {
            uint32_t u = __float_as_uint(src[j]);
            uint32_t r = (u + 0x7FFFu + ((u >> 16) & 1u)) >> 16;   // RN to bf16
            dst[j] = (u16t)r;
        }
    } else {
        int idx = (bid - 32) * 256 + threadIdx.x;  // 0..767 (chunks of 8 f32)
        const float4* s = (const float4*)W2d + idx * 2;
        float4 A = s[0], B = s[1];
        uint4 p;
        p.x = pk_bf16(A.x, A.y); p.y = pk_bf16(A.z, A.w);
        p.z = pk_bf16(B.x, B.y); p.w = pk_bf16(B.z, B.w);
        W2b[idx] = p;
    }
}

// ---------------------------------------------------------------------------
// Fused kernel: one block (256 thr) per (b,h).
//  phase 0: issue 12 staging float4 loads + 48 phase-4 column loads (ILP)
//  phase 1: stage x -> bf16 LDS xs16[32][392]
//  phase 2: y = W2d . x^T via mfma_16x16x32_bf16 (per-wave dup, e-slice write)
//  phase 2.5: convert column loads -> phase-4 B fragments (registers)
//  phase 3: conv1d + softmax (VALU) -> attn bf16 zs16[32][40]
//  phase 4: out = attn . x via mfma_32x32x16_bf16 (B from registers)
// LDS: 25088 + 2048 + 2560 = 29696 B.  Barriers: 2.  VGPR budget 128.
// ---------------------------------------------------------------------------
template <bool WBF>
__global__ void __launch_bounds__(256, 4) dynamixer_fused(
    const float* __restrict__ x,
    const float* __restrict__ W2d,
    const float* __restrict__ b2d,
    const float* __restrict__ W1d,
    const float* __restrict__ b1d,
    const u16t* __restrict__ Wt,
    const u16t* __restrict__ W2b,
    float* __restrict__ out)
{
    __shared__ u16t xs16[32 * 392];          // bf16 x tile, row stride 392
    __shared__ alignas(16) float ys[512];    // y, flat e*32+w
    __shared__ alignas(16) u16t zs16[32 * 40];  // attn bf16, row stride 40

    const int t = threadIdx.x;
    const int blk = blockIdx.x;                           // b*32 + h
    const float* __restrict__ xsrc = x + (size_t)blk * 12288;
    const int wid = t >> 6, lane = t & 63, g2 = lane >> 5, l31 = lane & 31;

    // ---------------- phase 0: issue all loads ----------------
    float4 st[12];
    {
        const float4* __restrict__ s4 = (const float4*)xsrc;
#pragma unroll
        for (int k = 0; k < 6; ++k) {
            st[2 * k]     = s4[512 * k + 2 * t];
            st[2 * k + 1] = s4[512 * k + 2 * t + 1];
        }
    }
    float xc[48];   // phase-4 B operand: x[v = h*16+g2*8+j][d = wid*96+i*32+l31]
    {
        const float* __restrict__ base = xsrc + wid * 96 + l31;
#pragma unroll
        for (int h = 0; h < 2; ++h)
#pragma unroll
            for (int j = 0; j < 8; ++j)
#pragma unroll
                for (int i = 0; i < 3; ++i)
                    xc[(h * 8 + j) * 3 + i] = base[(h * 16 + g2 * 8 + j) * 384 + i * 32];
    }

    // ---------------- phase 1: convert + stage x as bf16 ----------------
    {
#pragma unroll
        for (int k = 0; k < 6; ++k) {
            int p = t + (k << 8);
            int row = p / 48, c = p - row * 48;
            uint4 pk;
            pk.x = pk_bf16(st[2 * k].x,     st[2 * k].y);
            pk.y = pk_bf16(st[2 * k].z,     st[2 * k].w);
            pk.z = pk_bf16(st[2 * k + 1].x, st[2 * k + 1].y);
            pk.w = pk_bf16(st[2 * k + 1].z, st[2 * k + 1].w);
            *(uint4*)&xs16[row * 392 + c * 8] = pk;
        }
    }
    __syncthreads();

    // ---------------- phase 2: conv2d via MFMA 16x16x32 ----------------
    {
        const int g4 = lane >> 4, m = lane & 15;          // A row=e=m, B col=w=m
        f32x4 c0, c1;
#pragma unroll
        for (int r = 0; r < 4; ++r) { c0[r] = 0.f; c1[r] = 0.f; }
#pragma unroll 4
        for (int ks = 0; ks < 12; ++ks) {
            const int d0 = ks * 32 + g4 * 8;
            bf16x8 a;
            if (WBF) {
                a = *(const bf16x8*)&W2b[m * 384 + d0];
            } else {
                const float* wf = W2d + m * 384 + d0;
                float4 wa = *(const float4*)wf, wb = *(const float4*)(wf + 4);
                union { uint4 u; bf16x8 v; } cvt;
                cvt.u.x = pk_bf16(wa.x, wa.y); cvt.u.y = pk_bf16(wa.z, wa.w);
                cvt.u.z = pk_bf16(wb.x, wb.y); cvt.u.w = pk_bf16(wb.z, wb.w);
                a = cvt.v;
            }
            bf16x8 b0 = *(const bf16x8*)&xs16[m * 392 + d0];
            bf16x8 b1 = *(const bf16x8*)&xs16[(m + 16) * 392 + d0];
            c0 = __builtin_amdgcn_mfma_f32_16x16x32_bf16(a, b0, c0, 0, 0, 0);
            c1 = __builtin_amdgcn_mfma_f32_16x16x32_bf16(a, b1, c1, 0, 0, 0);
        }
        // write only this wave's e-slice [4*wid, 4*wid+4): C row=(l>>4)*4+r
        if (g4 == wid) {
            float4 bb = *(const float4*)&b2d[wid * 4];
            float bbv[4] = {bb.x, bb.y, bb.z, bb.w};
#pragma unroll
            for (int r = 0; r < 4; ++r) {
                ys[(4 * wid + r) * 32 + m]      = c0[r] + bbv[r];
                ys[(4 * wid + r) * 32 + 16 + m] = c1[r] + bbv[r];
            }
        }
    }

    // ---------------- phase 2.5: build phase-4 B fragments ----------------
    bf16x8 Bf[6];                                          // [h][i]
    {
#pragma unroll
        for (int h = 0; h < 2; ++h)
#pragma unroll
            for (int i = 0; i < 3; ++i) {
                union { uint4 u; bf16x8 v; } cv;
                cv.u.x = pk_bf16(xc[h * 24 + 0 * 3 + i], xc[h * 24 + 1 * 3 + i]);
                cv.u.y = pk_bf16(xc[h * 24 + 2 * 3 + i], xc[h * 24 + 3 * 3 + i]);
                cv.u.z = pk_bf16(xc[h * 24 + 4 * 3 + i], xc[h * 24 + 5 * 3 + i]);
                cv.u.w = pk_bf16(xc[h * 24 + 6 * 3 + i], xc[h * 24 + 7 * 3 + i]);
                Bf[h * 3 + i] = cv.v;
            }
    }
    asm volatile("s_waitcnt lgkmcnt(0)" ::: "memory");     // ys visible intra-wave
    __builtin_amdgcn_sched_barrier(0);

    // ---------------- phase 3: conv1d (z) + softmax -> attn bf16 ----------
    {
        const int g = t >> 5, l = t & 31;
        float2 ac2[4];
#pragma unroll
        for (int j = 0; j < 4; ++j) ac2[j] = make_float2(0.f, 0.f);
        if (WBF) {
            const uint4* __restrict__ wpt = (const uint4*)Wt + (g << 10);
#pragma unroll
            for (int k = 0; k < 8; ++k) {
                const float2* yp = (const float2*)&ys[(g << 6) + (k << 3)];
                float2 y0 = yp[0], y1 = yp[1], y2 = yp[2], y3 = yp[3];
#pragma unroll
                for (int j = 0; j < 4; ++j) {
                    uint4 wq = wpt[(k << 7) + l + (j << 5)];
                    ac2[j] += up2(wq.x) * y0;
                    ac2[j] += up2(wq.y) * y1;
                    ac2[j] += up2(wq.z) * y2;
                    ac2[j] += up2(wq.w) * y3;
                }
            }
        } else {
#pragma unroll
            for (int k = 0; k < 8; ++k) {
                const float2* yp = (const float2*)&ys[(g << 6) + (k << 3)];
                float2 y0 = yp[0], y1 = yp[1], y2 = yp[2], y3 = yp[3];
#pragma unroll
                for (int j = 0; j < 4; ++j) {
                    const float2* wr = (const float2*)(W1d + (((g << 7) + l + (j << 5)) << 6) + (k << 3));
                    ac2[j] += wr[0] * y0;
                    ac2[j] += wr[1] * y1;
                    ac2[j] += wr[2] * y2;
                    ac2[j] += wr[3] * y3;
                }
            }
        }
        float acc[4];
#pragma unroll
        for (int j = 0; j < 4; ++j)
            acc[j] = ac2[j].x + ac2[j].y + b1d[(g << 7) + (j << 5) + l];

        // softmax over v (= lane within 32-lane group), row u = 4g+j
#pragma unroll
        for (int j = 0; j < 4; ++j) {
            float mx = acc[j];
#pragma unroll
            for (int s = 16; s >= 1; s >>= 1) mx = fmaxf(mx, __shfl_xor(mx, s, 32));
            float p = __expf(acc[j] - mx);
            float ssum = p;
#pragma unroll
            for (int s = 16; s >= 1; s >>= 1) ssum += __shfl_xor(ssum, s, 32);
            float pv = __fdividef(p, ssum);
            zs16[((g << 2) + j) * 40 + l] = (u16t)pk_bf16(pv, pv);
        }
    }
    __syncthreads();

    // ---------------- phase 4: out = attn . x via MFMA 32x32x16 ----------
    {
        // A frags: attn[u = l31][k = g2*8 + j (+16)]
        bf16x8 A0 = *(const bf16x8*)&zs16[l31 * 40 + g2 * 8];
        bf16x8 A1 = *(const bf16x8*)&zs16[l31 * 40 + 16 + g2 * 8];
        float* __restrict__ obase = out + (size_t)blk * 12288;
#pragma unroll
        for (int i = 0; i < 3; ++i) {
            f32x16 acc16;
#pragma unroll
            for (int r = 0; r < 16; ++r) acc16[r] = 0.f;
            acc16 = __builtin_amdgcn_mfma_f32_32x32x16_bf16(A0, Bf[i],     acc16, 0, 0, 0);
            acc16 = __builtin_amdgcn_mfma_f32_32x32x16_bf16(A1, Bf[3 + i], acc16, 0, 0, 0);
            const int d = wid * 96 + i * 32 + l31;
#pragma unroll
            for (int r = 0; r < 16; ++r) {
                const int u = (r & 3) + 8 * (r >> 2) + 4 * g2;
                obase[u * 384 + d] = acc16[r];
            }
        }
    }
}

// ---------------------------------------------------------------------------
extern "C" void kernel_launch(void* const* d_in, const int* in_sizes, int n_in,
                              void* d_out, int out_size, void* d_ws, size_t ws_size,
                              hipStream_t stream) {
    const float* x   = (const float*)d_in[0];
    const float* W2d = (const float*)d_in[1];
    const float* b2d = (const float*)d_in[2];
    const float* W1d = (const float*)d_in[3];
    const float* b1d = (const float*)d_in[4];
    float* out = (float*)d_out;

    const size_t wt_bytes  = 8 * 8 * 128 * 8 * sizeof(u16t);   // 131072
    const size_t w2b_bytes = 16 * 384 * sizeof(u16t);          // 12288
    if (ws_size >= wt_bytes + w2b_bytes) {
        u16t* Wt = (u16t*)d_ws;
        u16t* W2b = (u16t*)((char*)d_ws + wt_bytes);
        prep_weights<<<35, 256, 0, stream>>>(W1d, W2d, Wt, (uint4*)W2b);
        dynamixer_fused<true><<<4096, 256, 0, stream>>>(x, W2d, b2d, W1d, b1d, Wt, W2b, out);
    } else {
        dynamixer_fused<false><<<4096, 256, 0, stream>>>(x, W2d, b2d, W1d, b1d, nullptr, nullptr, out);
    }
}